// Round 6
// baseline (102.806 us; speedup 1.0000x reference)
//
#include <hip/hip_runtime.h>
#include <math.h>

// Problem constants (B=2, D=512, K=32, H=W=64 -> N=4096)
#define B_DIM 2
#define D_DIM 512
#define K_DIM 32
#define N_DIM 4096

typedef float v2f __attribute__((ext_vector_type(2)));

// packed fp32 FMA, broadcasting src1's LO half to both lanes: d += a * b.lo
__device__ __forceinline__ void pk_bl(v2f& d, v2f a, v2f b) {
    asm("v_pk_fma_f32 %0, %1, %2, %0 op_sel:[0,0,0] op_sel_hi:[1,0,1]"
        : "+v"(d) : "v"(a), "v"(b));
}
// broadcast src1's HI half: d += a * b.hi
__device__ __forceinline__ void pk_bh(v2f& d, v2f a, v2f b) {
    asm("v_pk_fma_f32 %0, %1, %2, %0 op_sel:[0,1,0] op_sel_hi:[1,1,1]"
        : "+v"(d) : "v"(a), "v"(b));
}

// ---------------------------------------------------------------------------
// K0 prep: A[d,k] = s^2, B2[d,k] = -2 s^2 c, CK[k] = sum_d s^2 c^2;
// zeroes nsq + cnt (first 128 floats of ws). grid 64 x 256. (verified in R3)
// ---------------------------------------------------------------------------
__global__ __launch_bounds__(256)
void k_prep(const float* __restrict__ CW, const float* __restrict__ SC,
            float* __restrict__ A, float* __restrict__ B2,
            float* __restrict__ CK, float* __restrict__ zeroes)
{
    __shared__ float ckred[8][33];
    const int tid = threadIdx.x;
    const int idx = blockIdx.x * 256 + tid;      // d*32 + k
    const int d = idx >> 5, k = idx & 31;
    float s = SC[idx];
    float c = CW[k * D_DIM + d];
    float a = s * s;
    A[idx]  = a;
    B2[idx] = -2.f * a * c;
    if (blockIdx.x == 0) {                       // block-uniform branch
        if (tid < 128) zeroes[tid] = 0.f;        // nsq (64) + cnt + pad
        const int kk = tid & 31, g = tid >> 5;
        float acc = 0.f;
        for (int dd = g * 64; dd < g * 64 + 64; ++dd) {
            float sv = SC[dd * K_DIM + kk];
            float cv = CW[kk * D_DIM + dd];
            acc = fmaf(sv * sv * cv, cv, acc);
        }
        ckred[g][kk] = acc;
        __syncthreads();
        if (tid < 32) {
            float t = 0.f;
#pragma unroll
            for (int i = 0; i < 8; ++i) t += ckred[i][tid];
            CK[tid] = t;
        }
    }
}

// ---------------------------------------------------------------------------
// K1 v3: distances + softmax Q — serial-d GEMM microkernel, NO cross-lane
// reduction in the hot path (zero shfl until softmax), tables streamed from
// L2 (A-row d = 32k*4B = exactly one 128B line).
// grid = 512 = B * 256 n-tiles of 16; block 256 thr.
// Thread (ks=tid&7, ng=(tid>>3)&3, dsl=tid>>5): 4n x 4k tile, 64-d slice
// accumulated serially in registers. dsl-partials reduced via one small LDS
// array + barrier; softmax over k=32 via shfl (10 per thread, epilogue only).
// LDS 50 KB -> 3 blocks/CU capacity; ~60 VGPR.
// ---------------------------------------------------------------------------
__global__ __launch_bounds__(256, 2)
void k_dist_q(const float* __restrict__ X, const float* __restrict__ At,
              const float* __restrict__ Bt, const float* __restrict__ CK,
              float* __restrict__ Qout)
{
    __shared__ __align__(16) float xlds[D_DIM * 16];    // [d 512][n 16]
    __shared__ __align__(16) float part[8 * 16 * 36];   // [dsl 8][n 16][k 32 +4]

    const int tid = threadIdx.x;
    const int b  = blockIdx.x >> 8;
    const int n0 = (blockIdx.x & 255) << 4;   // 16 n per block

    // ---- stage 16 n x 512 d as [d][n]; 64-B coalesced, no transpose ----
    const float* xsrc = X + (size_t)b * D_DIM * N_DIM + n0;
#pragma unroll
    for (int j = 0; j < 8; ++j) {
        const int d  = (tid >> 2) + (j << 6);
        const int n4 = (tid & 3) << 2;
        *(float4*)(&xlds[d * 16 + n4]) =
            *(const float4*)(xsrc + (size_t)d * N_DIM + n4);
    }

    const int ks  = tid & 7;          // k0 = 4*ks
    const int ng  = (tid >> 3) & 3;   // n-base = 4*ng
    const int dsl = tid >> 5;         // d-base = 64*dsl

    float acc[4][4];
#pragma unroll
    for (int n = 0; n < 4; ++n)
#pragma unroll
        for (int k = 0; k < 4; ++k) acc[n][k] = 0.f;

    const float* arow = At + ((dsl << 6) * K_DIM) + (ks << 2);
    const float* brow = Bt + ((dsl << 6) * K_DIM) + (ks << 2);
    __syncthreads();
    const float* xrow = &xlds[(dsl << 6) * 16 + (ng << 2)];

    for (int i = 0; i < 64; i += 8) {
#pragma unroll
        for (int u = 0; u < 8; ++u) {
            const int d = i + u;
            float4 a4 = *(const float4*)(arow + d * K_DIM);
            float4 b4 = *(const float4*)(brow + d * K_DIM);
            float4 x4 = *(const float4*)(xrow + d * 16);
            float av[4] = {a4.x, a4.y, a4.z, a4.w};
            float bv[4] = {b4.x, b4.y, b4.z, b4.w};
            float xv[4] = {x4.x, x4.y, x4.z, x4.w};
#pragma unroll
            for (int n = 0; n < 4; ++n) {
                const float x  = xv[n];
                const float x2 = x * x;
#pragma unroll
                for (int k = 0; k < 4; ++k)
                    acc[n][k] = fmaf(av[k], x2, fmaf(bv[k], x, acc[n][k]));
            }
        }
    }

    // ---- dsl-partials to LDS (b128, bank-uniform) ----
    __syncthreads();   // xlds reads done before part overlaps? (separate arrays; barrier orders part writes vs softmax reads only)
#pragma unroll
    for (int nj = 0; nj < 4; ++nj)
        *(float4*)(&part[(dsl * 16 + (ng << 2) + nj) * 36 + (ks << 2)]) =
            make_float4(acc[nj][0], acc[nj][1], acc[nj][2], acc[nj][3]);
    __syncthreads();

    // ---- reduce 8 dsl + CK + softmax over k (32-lane groups), 2 passes ----
#pragma unroll
    for (int h = 0; h < 2; ++h) {
        const int n = (tid >> 5) + (h << 3);
        const int k = tid & 31;
        float dsum = CK[k];
#pragma unroll
        for (int i = 0; i < 8; ++i) dsum += part[(i * 16 + n) * 36 + k];
        float m = dsum;
#pragma unroll
        for (int mk = 16; mk >= 1; mk >>= 1)
            m = fminf(m, __shfl_xor(m, mk));
        float e = __expf(-0.5f * (dsum - m));
        float ssum = e;
#pragma unroll
        for (int mk = 16; mk >= 1; mk >>= 1)
            ssum += __shfl_xor(ssum, mk);
        Qout[((size_t)b * N_DIM + n0 + n) * K_DIM + k] = __fdividef(e, ssum);
    }
}

// ---------------------------------------------------------------------------
// K2: T partials + per-slab Q mass. T[b,d,k] = sum_n Q[b,n,k] * X[b,d,n],
// n split 32 ways. grid = 512 = b(2) x dtile(8 of 64 d) x ns(32 of 128 n).
// (unchanged from R5 — known-good)
// ---------------------------------------------------------------------------
__global__ __launch_bounds__(256, 2)
void k_tpart(const float* __restrict__ X, const float* __restrict__ Qin,
             float* __restrict__ TP, float* __restrict__ Mpart)
{
    __shared__ __align__(16) float Xs[64 * 68];        // [d 64][n 64 +4]
    __shared__ __align__(16) float Qs[64 * 36];        // [n 64][k 32 +4]
    __shared__ __align__(16) float red4[4 * 64 * 36];  // [wave][d 64][k 32 +4]
    __shared__ float mred[8][33];

    const int tid = threadIdx.x;
    const int bid = blockIdx.x;
    const int ns = bid & 31;
    const int dt = (bid >> 5) & 7;
    const int b  = bid >> 8;
    const int nsub = tid >> 5;
    const int dp = tid & 7;
    const int kp = (tid >> 3) & 3;
    const int k0t = kp << 3;           // contiguous 8-k slice
    const int wv = tid >> 6;

    v2f acc2[8][4];                    // [i over d][j2 over k-pairs]
#pragma unroll
    for (int i = 0; i < 8; ++i)
#pragma unroll
        for (int j = 0; j < 4; ++j) acc2[i][j] = (v2f)(0.f);

    const float* xsrc = X + ((size_t)b * D_DIM + dt * 64) * N_DIM + ns * 128;
    const float* qsrc = Qin + ((size_t)b * N_DIM + ns * 128) * K_DIM;

    for (int ch = 0; ch < 2; ++ch) {   // 2 chunks of 64 n
        __syncthreads();
#pragma unroll
        for (int i = 0; i < 4; ++i) {  // stage Xs: 64 d x 64 n
            int flat4 = tid + (i << 8);
            int row = flat4 >> 4;
            int c4  = (flat4 & 15) << 2;
            float4 v = *(const float4*)(xsrc + (size_t)row * N_DIM + (ch << 6) + c4);
            *(float4*)(&Xs[row * 68 + c4]) = v;
        }
#pragma unroll
        for (int i = 0; i < 2; ++i) {  // stage Qs [n][k]: direct, coalesced
            int flat4 = tid + (i << 8);
            int nn = flat4 >> 3;
            int k4 = (flat4 & 7) << 2;
            *(float4*)(&Qs[nn * 36 + k4]) =
                *(const float4*)(qsrc + ((ch << 6) + nn) * K_DIM + k4);
        }
        __syncthreads();
#pragma unroll
        for (int s = 0; s < 2; ++s) {
            const int nb = (nsub << 3) + (s << 2);
            float4 xr[8];
#pragma unroll
            for (int i = 0; i < 8; ++i)
                xr[i] = *(const float4*)(&Xs[(dp + (i << 3)) * 68 + nb]);
#pragma unroll
            for (int n = 0; n < 4; ++n) {
                float4 qa = *(const float4*)(&Qs[(nb + n) * 36 + k0t]);
                float4 qb = *(const float4*)(&Qs[(nb + n) * 36 + k0t + 4]);
                v2f q2[4] = {{qa.x, qa.y}, {qa.z, qa.w}, {qb.x, qb.y}, {qb.z, qb.w}};
#pragma unroll
                for (int i = 0; i < 8; ++i) {
                    v2f xlo = {xr[i].x, xr[i].y};
                    v2f xhi = {xr[i].z, xr[i].w};
                    v2f xb2 = (n < 2) ? xlo : xhi;
                    if ((n & 1) == 0) {
#pragma unroll
                        for (int j = 0; j < 4; ++j) pk_bl(acc2[i][j], q2[j], xb2);
                    } else {
#pragma unroll
                        for (int j = 0; j < 4; ++j) pk_bh(acc2[i][j], q2[j], xb2);
                    }
                }
            }
        }
    }
    // pair-reduce nsub (2w, 2w+1) via shfl, then per-wave slabs (no atomics)
    __syncthreads();
#pragma unroll
    for (int i = 0; i < 8; ++i)
#pragma unroll
        for (int j = 0; j < 4; ++j) {
            acc2[i][j].x += __shfl_xor(acc2[i][j].x, 32);
            acc2[i][j].y += __shfl_xor(acc2[i][j].y, 32);
        }
    if ((tid & 32) == 0) {
#pragma unroll
        for (int i = 0; i < 8; ++i) {
            float* r = &red4[(wv * 64 + dp + (i << 3)) * 36 + k0t];
            *(float4*)(r)     = make_float4(acc2[i][0].x, acc2[i][0].y,
                                            acc2[i][1].x, acc2[i][1].y);
            *(float4*)(r + 4) = make_float4(acc2[i][2].x, acc2[i][2].y,
                                            acc2[i][3].x, acc2[i][3].y);
        }
    }
    __syncthreads();
    // sum 4 wave slabs, store 64x32 tile (coalesced)
    float* dst = TP + (((size_t)ns * 2 + b) * D_DIM + dt * 64) * K_DIM;
#pragma unroll
    for (int e = 0; e < 8; ++e) {
        int flat = tid + (e << 8);          // 2048 cells
        int dl = flat >> 5;
        int k  = flat & 31;
        float s = red4[(0 * 64 + dl) * 36 + k] + red4[(1 * 64 + dl) * 36 + k]
                + red4[(2 * 64 + dl) * 36 + k] + red4[(3 * 64 + dl) * 36 + k];
        dst[dl * K_DIM + k] = s;
    }
    // dt==0 blocks: per-slab Q mass (L2-hot coalesced reads, no atomics)
    if (dt == 0) {
        const int k = tid & 31, g = tid >> 5;
        float qm = 0.f;
#pragma unroll
        for (int n = 0; n < 16; ++n)
            qm += qsrc[(g * 16 + n) * K_DIM + k];
        mred[g][k] = qm;
        __syncthreads();
        if (tid < K_DIM) {
            float t = 0.f;
#pragma unroll
            for (int i = 0; i < 8; ++i) t += mred[i][tid];
            Mpart[(ns * B_DIM + b) * K_DIM + tid] = t;
        }
    }
}

// ---------------------------------------------------------------------------
// K3 (fused zpre+zfin): z in registers, nsq via device atomics, grid-wide
// completion via agent-scope counter (128 blocks co-resident), then
// Z = z * rsqrt(nsq). (unchanged from R5 — known-good; cnt zeroed by k_prep)
// ---------------------------------------------------------------------------
__global__ __launch_bounds__(256)
void k_zfuse(const float* __restrict__ TP, const float* __restrict__ Mpart,
             const float* __restrict__ CW, const float* __restrict__ SC,
             float* __restrict__ Z, float* __restrict__ nsq, int* __restrict__ cnt)
{
    __shared__ float part[8][33];
    const int tid = threadIdx.x;
    const int b  = blockIdx.x >> 6;
    const int ds = blockIdx.x & 63;
    const int d  = (ds << 3) + (tid >> 5);
    const int k  = tid & 31;
    float sum = 0.f;
#pragma unroll
    for (int ns = 0; ns < 32; ++ns)
        sum += TP[(((size_t)ns * 2 + b) * D_DIM + d) * K_DIM + k];
    float m = 0.f;
#pragma unroll
    for (int ns = 0; ns < 32; ++ns)
        m += Mpart[(ns * B_DIM + b) * K_DIM + k];
    float c = CW[k * D_DIM + d];
    float s = SC[d * K_DIM + k];
    float z = s * (sum / m - c);
    part[tid >> 5][k] = z * z;
    __syncthreads();
    if (tid < K_DIM) {
        float t = 0.f;
#pragma unroll
        for (int i = 0; i < 8; ++i) t += part[i][tid];
        atomicAdd(&nsq[b * K_DIM + tid], t);
    }
    __syncthreads();   // barrier drains this block's atomics
    if (tid == 0) {
        __hip_atomic_fetch_add(cnt, 1, __ATOMIC_ACQ_REL, __HIP_MEMORY_SCOPE_AGENT);
        while (__hip_atomic_load(cnt, __ATOMIC_ACQUIRE, __HIP_MEMORY_SCOPE_AGENT) < 128)
            __builtin_amdgcn_s_sleep(1);
    }
    __syncthreads();
    float nv = __hip_atomic_load(&nsq[b * K_DIM + k], __ATOMIC_RELAXED,
                                 __HIP_MEMORY_SCOPE_AGENT);
    Z[((b * D_DIM) + d) * K_DIM + k] = z * rsqrtf(nv);
}

extern "C" void kernel_launch(void* const* d_in, const int* in_sizes, int n_in,
                              void* d_out, int out_size, void* d_ws, size_t ws_size,
                              hipStream_t stream)
{
    const float* X  = (const float*)d_in[0];   // [2,512,64,64]
    const float* CW = (const float*)d_in[1];   // [32,512]
    const float* SC = (const float*)d_in[2];   // [512,32]
    float* Z = (float*)d_out;                              // [2,512,32]
    float* Q = (float*)d_out + B_DIM * D_DIM * K_DIM;      // [2,4096,32]

    float* W    = (float*)d_ws;
    float* nsq  = W;                                       // 64 floats
    int*   cnt  = (int*)(W + 64);                          // 1 int
    float* Mpart= W + 128;                                 // 32*2*32 = 2048
    float* TP   = W + 128 + 2048;                          // 4 MB
    float* At   = TP + 32 * B_DIM * D_DIM * K_DIM;         // 16384 floats
    float* Bt   = At + D_DIM * K_DIM;                      // 16384 floats
    float* CKt  = Bt + D_DIM * K_DIM;                      // 32 floats

    k_prep  <<< 64, 256, 0, stream>>>(CW, SC, At, Bt, CKt, W);
    k_dist_q<<<512, 256, 0, stream>>>(X, At, Bt, CKt, Q);
    k_tpart <<<512, 256, 0, stream>>>(X, Q, TP, Mpart);
    k_zfuse <<<128, 256, 0, stream>>>(TP, Mpart, CW, SC, Z, nsq, cnt);
}